// Round 6
// baseline (941.878 us; speedup 1.0000x reference)
//
#include <hip/hip_runtime.h>
#include <hip/hip_bf16.h>

#define MDIM 4096
#define DDIM 2048
#define HDIM 2048
#define EDIM 8
#define HD   ((size_t)HDIM * DDIM)

typedef float v4f __attribute__((ext_vector_type(4)));
typedef int   v4i __attribute__((ext_vector_type(4)));
typedef int   v8i __attribute__((ext_vector_type(8)));

// async global->LDS, 16B per lane. lds pointer must be wave-uniform
// (HW writes base + lane*16).
__device__ __forceinline__ void gl2lds16(const void* g, void* l) {
  __builtin_amdgcn_global_load_lds(
      (const __attribute__((address_space(1))) void*)g,
      (__attribute__((address_space(3))) void*)l,
      16, 0, 0);
}

__device__ __forceinline__ unsigned int pk_bf16(float a, float b) {
  __hip_bfloat16 ha = __float2bfloat16(a), hb = __float2bfloat16(b);
  unsigned short ua = *(unsigned short*)&ha, ub = *(unsigned short*)&hb;
  return (unsigned int)ua | ((unsigned int)ub << 16);
}
__device__ __forceinline__ float ubf_lo(unsigned int u) {
  return __int_as_float((int)(u << 16));
}
__device__ __forceinline__ float ubf_hi(unsigned int u) {
  return __int_as_float((int)(u & 0xFFFF0000u));
}

// ---------------- Kernel 1: gating softmax + fp8 quantize of x ----------------
__global__ __launch_bounds__(256) void k_gate_xq(
    const float* __restrict__ x, const float* __restrict__ gw,
    const float* __restrict__ gb, float* __restrict__ gate,
    unsigned char* __restrict__ x8)
{
  const int wid  = threadIdx.x >> 6;
  const int lane = threadIdx.x & 63;
  const int m    = blockIdx.x * 4 + wid;

  const float4* xr = (const float4*)(x + (size_t)m * DDIM);
  unsigned int* qr = (unsigned int*)(x8 + (size_t)m * DDIM);

  float part[EDIM];
#pragma unroll
  for (int e = 0; e < EDIM; ++e) part[e] = 0.f;

#pragma unroll
  for (int it = 0; it < DDIM / 4 / 64; ++it) {   // 8 iterations
    const int idx = it * 64 + lane;
    const float4 xv = xr[idx];
    int pk = __builtin_amdgcn_cvt_pk_fp8_f32(xv.x, xv.y, 0, false);
    pk = __builtin_amdgcn_cvt_pk_fp8_f32(xv.z, xv.w, pk, true);
    qr[idx] = (unsigned int)pk;
#pragma unroll
    for (int e = 0; e < EDIM; ++e) {
      const float4 wv = ((const float4*)(gw + (size_t)e * DDIM))[idx];
      part[e] += xv.x * wv.x + xv.y * wv.y + xv.z * wv.z + xv.w * wv.w;
    }
  }
#pragma unroll
  for (int e = 0; e < EDIM; ++e) {
#pragma unroll
    for (int off = 32; off > 0; off >>= 1)
      part[e] += __shfl_xor(part[e], off);
  }
  float lg[EDIM];
  float s = 0.f;
#pragma unroll
  for (int e = 0; e < EDIM; ++e) lg[e] = part[e] + gb[e];
  float mx = lg[0];
#pragma unroll
  for (int e = 1; e < EDIM; ++e) mx = fmaxf(mx, lg[e]);
#pragma unroll
  for (int e = 0; e < EDIM; ++e) { lg[e] = expf(lg[e] - mx); s += lg[e]; }
  const float inv = 1.f / s;
  if (lane < EDIM) gate[m * EDIM + lane] = lg[lane] * inv;
}

// ---------------- Kernel 2: fp8 quantize of expert_w --------------------------
__global__ void k_wq(const float* __restrict__ w, unsigned char* __restrict__ w8)
{
  const long long n4 = (long long)EDIM * HDIM * DDIM / 4;
  const long long stride = (long long)gridDim.x * blockDim.x;
  for (long long i = (long long)blockIdx.x * blockDim.x + threadIdx.x; i < n4;
       i += stride) {
    const float4 v = ((const float4*)w)[i];
    int pk = __builtin_amdgcn_cvt_pk_fp8_f32(v.x, v.y, 0, false);
    pk = __builtin_amdgcn_cvt_pk_fp8_f32(v.z, v.w, pk, true);
    ((unsigned int*)w8)[i] = (unsigned int)pk;
  }
}

// ---------------- Kernel 3: fused grouped GEMM + gated combine ----------------
// 512 threads (8 waves, 2m x 4n), block tile 256x256, per-wave 128x64, BK=128.
// 2-way EXPERT SPLIT: block p in {0,1} handles experts 4p..4p+3; both halves
// atomicAdd f32 partials into zero-init'd out (2 commutative contributors per
// address -> bitwise deterministic).
// Key restructure vs R5: no per-expert accumulator. Each fragment's K-tile
// contribution is ONE mfma_scale (K=128=BK) into zero-C; gate (bf16-packed,
// hoisted per expert segment) is FMA'd into the single outacc. This frees
// 128 VGPRs -> per-wave tile 2x bigger -> LDS bytes/FLOP 0.75x -> matrix-bound.
// T2 both-sides XOR swizzle; T1 XCD chunking (p-pairs co-located for A/out L2
// sharing); dbuf counted vmcnt(8) (compute phase ~2200cyc >> HBM latency).
__global__ __launch_bounds__(512, 2) void k_moe_gemm(
    const unsigned char* __restrict__ x8,   // [M, D]
    const unsigned char* __restrict__ w8,   // [E, H, D]
    const float* __restrict__ gate,         // [M, 8]
    float* __restrict__ out)                // [M, H] f32 (zero-initialized)
{
  extern __shared__ unsigned char smem[];   // 2*65536 + 4096 = 135168 B

  const int tid  = threadIdx.x;
  const int lane = tid & 63;
  const int wid  = tid >> 6;
  const int wm   = wid >> 2;        // 0..1  (128-row group)
  const int wn   = wid & 3;         // 0..3  (64-col group)

  // XCD chunking: xcd = bid&7; local = bid>>3: p = local&1 (expert half),
  // idx = local>>1 -> 4x4 tile square per XCD; p-pairs adjacent (share A,out).
  const int bid   = blockIdx.x;
  const int xcd   = bid & 7;
  const int local = bid >> 3;                  // 0..31
  const int p     = local & 1;
  const int idx   = local >> 1;                // 0..15
  const int tm    = (xcd >> 1) * 4 + (idx >> 2);   // 0..15
  const int tn    = (xcd & 1) * 4 + (idx & 3);     // 0..7
  const int bm    = tm * 256;
  const int bn    = tn * 256;

  const int lrow = lane & 15;
  const int lk   = lane >> 4;             // 0..3 -> k-block of 32 bytes
  const int swz  = (lrow & 7) << 4;
  const int c0   = (lk * 32) ^ swz;       // swizzled 16B chunk cols
  const int c1   = c0 ^ 16;

  // staging source coords: per thread row strow, inverse-swizzled col stcol
  const int strow = tid >> 3;
  const int stcol = ((tid & 7) * 16) ^ ((strow & 7) << 4);
  const unsigned char* asrc = x8 + (size_t)(bm + strow) * DDIM + stcol;
  const unsigned char* bsrc = w8 + (size_t)p * 4 * HD +
                              (size_t)(bn + strow) * DDIM + stcol;

  float* sGf = (float*)(smem + 131072);   // [4 experts][256 rows] f32

  // prologue: gate cache (this block's 4 experts, transposed for b128 reads)
  if (tid < 256) {
    const float4 gv = *(const float4*)(gate + (size_t)(bm + tid) * EDIM + p * 4);
    sGf[0 * 256 + tid] = gv.x;
    sGf[1 * 256 + tid] = gv.y;
    sGf[2 * 256 + tid] = gv.z;
    sGf[3 * 256 + tid] = gv.w;
  }

  v4f outacc[8][4];
#pragma unroll
  for (int i = 0; i < 8; ++i)
#pragma unroll
    for (int j = 0; j < 4; ++j) {
      outacc[i][j][0] = 0.f; outacc[i][j][1] = 0.f;
      outacc[i][j][2] = 0.f; outacc[i][j][3] = 0.f;
    }
  unsigned int gpk[8][2];
  const v4f zero4 = {0.f, 0.f, 0.f, 0.f};

#define STAGE(T, RB) do {                                                      \
    const int e_ = (T) >> 4;                                                   \
    const int k_ = ((T) & 15) * 128;                                           \
    const size_t bo_ = (size_t)e_ * HD + (size_t)k_;                           \
    _Pragma("unroll") for (int s = 0; s < 4; ++s)                              \
      gl2lds16(asrc + (size_t)s * (64 * DDIM) + k_,                            \
               (void*)(smem + (RB) * 65536 + s * 8192 + wid * 1024));          \
    _Pragma("unroll") for (int s = 0; s < 4; ++s)                              \
      gl2lds16(bsrc + (size_t)s * (64 * DDIM) + bo_,                           \
               (void*)(smem + (RB) * 65536 + 32768 + s * 8192 + wid * 1024));  \
  } while (0)

#define COMP(RB, T) do {                                                       \
    if (((T) & 15) == 0) {      /* hoist gates for this expert segment */      \
      const int e_ = (T) >> 4;                                                 \
      _Pragma("unroll") for (int i = 0; i < 8; ++i) {                          \
        const v4f g4 =                                                         \
            *(const v4f*)(sGf + e_ * 256 + wm * 128 + i * 16 + lk * 4);        \
        gpk[i][0] = pk_bf16(g4[0], g4[1]);                                     \
        gpk[i][1] = pk_bf16(g4[2], g4[3]);                                     \
      }                                                                        \
    }                                                                          \
    const unsigned char* pA_ =                                                 \
        smem + (RB) * 65536 + (size_t)(wm * 128 + lrow) * 128;                 \
    const unsigned char* pB_ =                                                 \
        smem + (RB) * 65536 + 32768 + (size_t)(wn * 64 + lrow) * 128;          \
    v8i bv_[4];                                                                \
    _Pragma("unroll") for (int j = 0; j < 4; ++j) {                            \
      union { v8i v; v4i h[2]; } u_;                                           \
      u_.h[0] = *(const v4i*)(pB_ + j * 2048 + c0);                            \
      u_.h[1] = *(const v4i*)(pB_ + j * 2048 + c1);                            \
      bv_[j] = u_.v;                                                           \
    }                                                                          \
    __builtin_amdgcn_s_setprio(1);                                             \
    _Pragma("unroll") for (int i = 0; i < 8; ++i) {                            \
      union { v8i v; v4i h[2]; } ua_;                                          \
      ua_.h[0] = *(const v4i*)(pA_ + i * 2048 + c0);                           \
      ua_.h[1] = *(const v4i*)(pA_ + i * 2048 + c1);                           \
      const v8i av_ = ua_.v;                                                   \
      const float g0_ = ubf_lo(gpk[i][0]), g1_ = ubf_hi(gpk[i][0]);            \
      const float g2_ = ubf_lo(gpk[i][1]), g3_ = ubf_hi(gpk[i][1]);            \
      _Pragma("unroll") for (int j = 0; j < 4; ++j) {                          \
        const v4f t_ = __builtin_amdgcn_mfma_scale_f32_16x16x128_f8f6f4(       \
            av_, bv_[j], zero4, 0 /*fp8*/, 0 /*fp8*/,                          \
            0, 127 /*e8m0 1.0*/, 0, 127 /*e8m0 1.0*/);                         \
        outacc[i][j][0] += g0_ * t_[0];                                        \
        outacc[i][j][1] += g1_ * t_[1];                                        \
        outacc[i][j][2] += g2_ * t_[2];                                        \
        outacc[i][j][3] += g3_ * t_[3];                                        \
      }                                                                        \
    }                                                                          \
    __builtin_amdgcn_s_setprio(0);                                             \
  } while (0)

#define STEP(T, RB, WAIT, DOSTAGE) do {                                        \
    if (DOSTAGE) STAGE((T) + 1, (RB) ^ 1);                                     \
    asm volatile("s_waitcnt vmcnt(" #WAIT ")" ::: "memory");                   \
    __builtin_amdgcn_s_barrier();                                              \
    __builtin_amdgcn_sched_barrier(0);                                         \
    COMP((RB), (T));                                                           \
    __builtin_amdgcn_sched_barrier(0);                                         \
    __builtin_amdgcn_s_barrier();                                              \
  } while (0)

  STAGE(0, 0);
  __syncthreads();   // drains prologue loads + publishes sGf (once)

  for (int t = 0; t < 62; t += 2) {
    STEP(t, 0, 8, 1);
    STEP(t + 1, 1, 8, 1);
  }
  STEP(62, 0, 8, 1);
  STEP(63, 1, 0, 0);

#undef STEP
#undef COMP
#undef STAGE

  // epilogue: deterministic 2-contributor f32 atomic combine into out
#pragma unroll
  for (int i = 0; i < 8; ++i)
#pragma unroll
    for (int q = 0; q < 4; ++q) {
      const size_t r = (size_t)(bm + wm * 128 + i * 16 + lk * 4 + q);
      float* orow = out + r * HDIM + bn + wn * 64 + lrow;
#pragma unroll
      for (int j = 0; j < 4; ++j)
        atomicAdd(orow + j * 16, outacc[i][j][q]);
    }
}

extern "C" void kernel_launch(void* const* d_in, const int* in_sizes, int n_in,
                              void* d_out, int out_size, void* d_ws, size_t ws_size,
                              hipStream_t stream) {
  (void)in_sizes; (void)n_in; (void)out_size; (void)ws_size;
  const float* x        = (const float*)d_in[0];
  const float* gate_w   = (const float*)d_in[1];
  const float* gate_b   = (const float*)d_in[2];
  const float* expert_w = (const float*)d_in[3];
  float* out = (float*)d_out;

  char* ws = (char*)d_ws;
  float* gate       = (float*)ws;                                   // 131072 B
  unsigned char* x8 = (unsigned char*)(ws + 131072);                // 8 MiB
  unsigned char* w8 = (unsigned char*)(ws + 131072 + (size_t)MDIM * DDIM);

  hipMemsetAsync(d_out, 0, (size_t)MDIM * HDIM * sizeof(float), stream);
  hipLaunchKernelGGL(k_gate_xq, dim3(MDIM / 4), dim3(256), 0, stream,
                     x, gate_w, gate_b, gate, x8);
  hipLaunchKernelGGL(k_wq, dim3(4096), dim3(256), 0, stream, expert_w, w8);
  hipLaunchKernelGGL(k_moe_gemm, dim3(256), dim3(512), 135168, stream,
                     x8, w8, gate, out);
}